// Round 13
// baseline (639.188 us; speedup 1.0000x reference)
//
#include <hip/hip_runtime.h>
#include <hip/hip_bf16.h>
#include <math.h>

typedef __bf16 bf16;
typedef __bf16 bf16x4 __attribute__((ext_vector_type(4)));
typedef __bf16 bf16x8 __attribute__((ext_vector_type(8)));
typedef float f32x4 __attribute__((ext_vector_type(4)));

#define SEQ 1024
#define DMODEL 1024

// async global->LDS DMA, 16B per lane, dest = wave-uniform base + lane*16
__device__ __forceinline__ void gld_lds16(const bf16* g, bf16* l) {
    __builtin_amdgcn_global_load_lds(
        (const __attribute__((address_space(1))) unsigned int*)g,
        (__attribute__((address_space(3))) unsigned int*)l, 16, 0, 0);
}

// ---------------------------------------------------------------------------
// Fused transpose + fp32->bf16 convert: out[n*K + k] = (bf16)in[k*N + n]
// ---------------------------------------------------------------------------
__global__ void transpose_f2b(const float* __restrict__ in, bf16* __restrict__ out,
                              int K, int N) {
    __shared__ float tile[32][33];
    int n0 = blockIdx.x * 32, k0 = blockIdx.y * 32;
    int tx = threadIdx.x, ty = threadIdx.y;
#pragma unroll
    for (int i = 0; i < 4; ++i) {
        int kk = ty + i * 8;
        tile[kk][tx] = in[(size_t)(k0 + kk) * N + n0 + tx];
    }
    __syncthreads();
#pragma unroll
    for (int i = 0; i < 4; ++i) {
        int nn = ty + i * 8;
        out[(size_t)(n0 + nn) * K + k0 + tx] = (bf16)tile[tx][nn];
    }
}

// ---------------------------------------------------------------------------
// LayerNorm: fp32 in -> bf16 out. One row (D=1024) per 256-thread block.
// ---------------------------------------------------------------------------
__global__ void ln_f2b(const float* __restrict__ x, const float* __restrict__ g,
                       const float* __restrict__ bta, bf16* __restrict__ y) {
    int row = blockIdx.x, t = threadIdx.x;
    const float* xr = x + (size_t)row * DMODEL;
    float v[4];
#pragma unroll
    for (int i = 0; i < 4; ++i) v[i] = xr[t * 4 + i];
    float s = v[0] + v[1] + v[2] + v[3];
    float s2 = v[0] * v[0] + v[1] * v[1] + v[2] * v[2] + v[3] * v[3];
#pragma unroll
    for (int off = 32; off > 0; off >>= 1) {
        s += __shfl_down(s, off, 64);
        s2 += __shfl_down(s2, off, 64);
    }
    __shared__ float ws1[4], ws2[4];
    __shared__ float mu_s, rstd_s;
    int lane = t & 63, wv = t >> 6;
    if (lane == 0) { ws1[wv] = s; ws2[wv] = s2; }
    __syncthreads();
    if (t == 0) {
        float S1 = ws1[0] + ws1[1] + ws1[2] + ws1[3];
        float S2 = ws2[0] + ws2[1] + ws2[2] + ws2[3];
        float mu = S1 * (1.0f / DMODEL);
        float var = S2 * (1.0f / DMODEL) - mu * mu;
        mu_s = mu;
        rstd_s = rsqrtf(var + 1e-5f);
    }
    __syncthreads();
    float mu = mu_s, rstd = rstd_s;
    bf16* yr = y + (size_t)row * DMODEL;
#pragma unroll
    for (int i = 0; i < 4; ++i) {
        int d = t * 4 + i;
        float o = (v[i] - mu) * rstd * g[d] + bta[d];
        yr[d] = (bf16)o;
    }
}

// ---------------------------------------------------------------------------
// GEMM (128x128, m97 structure): C[M,N] = A[M,K](bf16) @ Bt[N,K](bf16)^T + bias
// mode: 0 = bf16 out, 1 = bf16 out + exact GELU, 2 = fp32 out
// ---------------------------------------------------------------------------
#define BM 128
#define BN 128
#define BK 32

__global__ __launch_bounds__(256, 2) void gemm_bt(
    const bf16* __restrict__ A, const bf16* __restrict__ Bt,
    const float* __restrict__ bias, void* __restrict__ Cv,
    int M, int N, int K, int mode) {
    __shared__ bf16 sA[BM * BK];   // row-major, 64B rows, chunk-swizzled
    __shared__ bf16 sB[BN * BK];
    int t = threadIdx.x;
    int lane = t & 63, wave = t >> 6;
    int wr = wave >> 1, wc = wave & 1;
    int m0 = blockIdx.y * BM, n0 = blockIdx.x * BN;
    const bf16* Ap = A + (size_t)m0 * K;
    const bf16* Bp = Bt + (size_t)n0 * K;

    int srow = wave * 16 + (lane >> 2);
    int schunk = lane & 3;
    int gcoff = (schunk ^ (srow & 3)) * 8;
    const bf16* gA0 = Ap + (size_t)srow * K + gcoff;
    const bf16* gA1 = Ap + (size_t)(srow + 64) * K + gcoff;
    const bf16* gB0 = Bp + (size_t)srow * K + gcoff;
    const bf16* gB1 = Bp + (size_t)(srow + 64) * K + gcoff;
    bf16* lA0 = sA + wave * 512;
    bf16* lA1 = sA + 2048 + wave * 512;
    bf16* lB0 = sB + wave * 512;
    bf16* lB1 = sB + 2048 + wave * 512;

    f32x4 acc[4][4];
#pragma unroll
    for (int i = 0; i < 4; ++i)
#pragma unroll
        for (int j = 0; j < 4; ++j) acc[i][j] = (f32x4){0.f, 0.f, 0.f, 0.f};

    int mq = lane & 15, quad = lane >> 4;
    int csw = (quad ^ (mq & 3)) * 8;

    for (int k0 = 0; k0 < K; k0 += BK) {
        __syncthreads();
        gld_lds16(gA0 + k0, lA0);
        gld_lds16(gA1 + k0, lA1);
        gld_lds16(gB0 + k0, lB0);
        gld_lds16(gB1 + k0, lB1);
        __syncthreads();
        bf16x8 af[4], bfr[4];
#pragma unroll
        for (int i = 0; i < 4; ++i)
            af[i] = *(const bf16x8*)&sA[(wr * 64 + i * 16 + mq) * BK + csw];
#pragma unroll
        for (int j = 0; j < 4; ++j)
            bfr[j] = *(const bf16x8*)&sB[(wc * 64 + j * 16 + mq) * BK + csw];
#pragma unroll
        for (int i = 0; i < 4; ++i)
#pragma unroll
            for (int j = 0; j < 4; ++j)
                acc[i][j] = __builtin_amdgcn_mfma_f32_16x16x32_bf16(af[i], bfr[j], acc[i][j], 0, 0, 0);
    }

    int cq = lane & 15, rq = (lane >> 4) * 4;
#pragma unroll
    for (int i = 0; i < 4; ++i) {
        int row = m0 + wr * 64 + i * 16 + rq;
#pragma unroll
        for (int j = 0; j < 4; ++j) {
            int col = n0 + wc * 64 + j * 16 + cq;
            float bv = bias ? bias[col] : 0.0f;
#pragma unroll
            for (int r = 0; r < 4; ++r) {
                float v = acc[i][j][r] + bv;
                if (mode == 1) v = 0.5f * v * (1.0f + erff(v * 0.70710678118654752f));
                size_t idx = (size_t)(row + r) * N + col;
                if (mode == 2) ((float*)Cv)[idx] = v;
                else           ((bf16*)Cv)[idx] = (bf16)v;
            }
        }
    }
}

// ---------------------------------------------------------------------------
// MFMA flash attention v6 = R9-verified v3 structure EXACTLY (K=32 MFMA PV,
// Plds round-trip, rotated V-scatter) + two VALU trims:
//  - exp2-domain softmax (proven in R11's passing v4): Q pre-scaled by
//    0.125*log2(e); exp2f = bare v_exp (saves 32 v_mul/tile); tree-max.
//  - T13 defer-max (THR=12 in exp2 domain ~ 8 nats): skip o_acc rescale +
//    4 alpha-shuffles + 16 muls when __all(mx - m_run <= THR). Wave-uniform
//    branch; deferred P <= 2^12 (bf16/f32 have ample range); l_run update
//    split as l*=alpha; l+=rs (equivalent).
// v5 post-mortem: ds_read_b64_tr_b16 layout assumption wrong (absmax 1.25)
// -> tr_read path abandoned (lane-mapping unresolvable without HW probe).
// v4 post-mortem: mfma16 PV doubled matrix-pipe time -> K=32 retained.
// ---------------------------------------------------------------------------
#define KVB 128
#define LDK2 72     // Klds row pad (d=64 -> 72)
#define LDP 136     // Vt/P row pad (key=128 -> 136)

__global__ __launch_bounds__(256, 2) void attn_mfma(const bf16* __restrict__ qkv,
                                                    bf16* __restrict__ ao) {
    __shared__ bf16 Klds[KVB][LDK2];    // [key][d]   18,432 B
    __shared__ bf16 Vtlds[64][LDP];     // [d][key]   17,408 B
    __shared__ bf16 Plds[4][16][LDP];   // per-wave P [q-row][key] 17,408 B
    int t = threadIdx.x, lane = t & 63, wave = t >> 6;

    // XCD swizzle: 256 consecutive flat ids per XCD -> all 16 q-tiles of a
    // (b,h) share one L2 copy of K/V (R5: FETCH 139->24.7 MB).
    int f = (int)blockIdx.y * (int)gridDim.x + (int)blockIdx.x;  // 0..2047
    int wg = (f & 7) * 256 + (f >> 3);
    int bh = wg >> 4, bb = bh >> 4, h = bh & 15;
    int q0 = (wg & 15) * 64;

    const bf16* base = qkv + (size_t)bb * SEQ * 3072;
    int m = lane & 15, quad = lane >> 4;
    int kq = quad * 8;

    bf16x8 qf[2];   // pre-scaled by 0.125*log2(e) -> softmax in exp2 domain
    {
        int qrow = q0 + wave * 16 + m;
        const bf16* p = base + (size_t)qrow * 3072 + h * 64;
#pragma unroll
        for (int c = 0; c < 2; ++c) {
            bf16x8 tmp = *(const bf16x8*)(p + c * 32 + kq);
#pragma unroll
            for (int j = 0; j < 8; ++j)
                qf[c][j] = (bf16)((float)tmp[j] * 0.18033688011112042f);
        }
    }

    float m_run = -3e38f, l_run = 0.f;
    f32x4 o_acc[4];
#pragma unroll
    for (int g = 0; g < 4; ++g) o_acc[g] = (f32x4){0.f, 0.f, 0.f, 0.f};

    // staging: thread covers K/V rows skey+{0,32,64,96}, d-slice sd0..sd0+8
    int skey = t >> 3, sd0 = (t & 7) * 8;
    int rot = t & 7;
    const bf16* pk0 = base + (size_t)skey * 3072 + 1024 + h * 64 + sd0;
    const bf16* pv0 = base + (size_t)skey * 3072 + 2048 + h * 64 + sd0;

    bf16x8 kreg[4], vreg[4];

#define LOADKV(kt2) do { \
    const bf16* pk = pk0 + (size_t)(kt2) * KVB * 3072; \
    const bf16* pv = pv0 + (size_t)(kt2) * KVB * 3072; \
    _Pragma("unroll") for (int c = 0; c < 4; ++c) { \
        kreg[c] = *(const bf16x8*)(pk + (size_t)c * 32 * 3072); \
        vreg[c] = *(const bf16x8*)(pv + (size_t)c * 32 * 3072); } \
} while (0)
#define WRITEKV() do { \
    _Pragma("unroll") for (int c = 0; c < 4; ++c) { \
        *(bf16x8*)&Klds[skey + c * 32][sd0] = kreg[c]; \
        _Pragma("unroll") for (int ii = 0; ii < 8; ++ii) { \
            int j = (ii + rot) & 7; \
            Vtlds[sd0 + j][skey + c * 32] = vreg[c][j]; } } \
} while (0)

    // prologue: tile 0 -> LDS
    LOADKV(0);
    WRITEKV();
    __syncthreads();

    for (int kt = 0; kt < SEQ / KVB; ++kt) {   // 8 iterations
        if (kt + 1 < SEQ / KVB) LOADKV(kt + 1);   // T14: issue early

        // swapped QK^T: s[g][r] = P[key=g*16+quad*4+r][q=m]  (exp2 domain)
        f32x4 s[8];
#pragma unroll
        for (int g = 0; g < 8; ++g) {
            bf16x8 b0 = *(const bf16x8*)&Klds[g * 16 + m][kq];
            bf16x8 b1 = *(const bf16x8*)&Klds[g * 16 + m][32 + kq];
            s[g] = (f32x4){0.f, 0.f, 0.f, 0.f};
            s[g] = __builtin_amdgcn_mfma_f32_16x16x32_bf16(b0, qf[0], s[g], 0, 0, 0);
            s[g] = __builtin_amdgcn_mfma_f32_16x16x32_bf16(b1, qf[1], s[g], 0, 0, 0);
        }

        // lane-local online softmax for q-row m (exp2 domain, tree max,
        // T13 defer-max)
        {
            float mg[8];
#pragma unroll
            for (int g = 0; g < 8; ++g)
                mg[g] = fmaxf(fmaxf(s[g][0], s[g][1]), fmaxf(s[g][2], s[g][3]));
            float mx = fmaxf(fmaxf(fmaxf(mg[0], mg[1]), fmaxf(mg[2], mg[3])),
                             fmaxf(fmaxf(mg[4], mg[5]), fmaxf(mg[6], mg[7])));
            mx = fmaxf(mx, __shfl_xor(mx, 16, 64));
            mx = fmaxf(mx, __shfl_xor(mx, 32, 64));
            if (!__all(mx - m_run <= 12.0f)) {
                float m_new = fmaxf(m_run, mx);
                float alpha = exp2f(m_run - m_new);
                m_run = m_new;
                l_run *= alpha;
                float av[4];
#pragma unroll
                for (int r = 0; r < 4; ++r) av[r] = __shfl(alpha, quad * 4 + r, 64);
#pragma unroll
                for (int g = 0; g < 4; ++g)
#pragma unroll
                    for (int r = 0; r < 4; ++r) o_acc[g][r] *= av[r];
            }
            float rs = 0.f;
#pragma unroll
            for (int g = 0; g < 8; ++g)
#pragma unroll
                for (int r = 0; r < 4; ++r) {
                    float p = exp2f(s[g][r] - m_run);
                    s[g][r] = p;
                    rs += p;
                }
            rs += __shfl_xor(rs, 16, 64);
            rs += __shfl_xor(rs, 32, 64);
            l_run += rs;
        }

        // P -> LDS: keys g*16+quad*4+{0..3} of row m, one b64 per g
#pragma unroll
        for (int g = 0; g < 8; ++g) {
            bf16x4 pw = {(bf16)s[g][0], (bf16)s[g][1], (bf16)s[g][2], (bf16)s[g][3]};
            *(bf16x4*)&Plds[wave][m][g * 16 + quad * 4] = pw;
        }

        // PV: 4 key-chunks of 32 (identical to verified v3)
#pragma unroll
        for (int kc = 0; kc < 4; ++kc) {
            bf16x8 pf = *(const bf16x8*)&Plds[wave][m][kc * 32 + kq];
#pragma unroll
            for (int dg = 0; dg < 4; ++dg) {
                bf16x8 vf = *(const bf16x8*)&Vtlds[dg * 16 + m][kc * 32 + kq];
                o_acc[dg] = __builtin_amdgcn_mfma_f32_16x16x32_bf16(pf, vf, o_acc[dg], 0, 0, 0);
            }
        }

        __syncthreads();                         // all waves done with tile kt
        if (kt + 1 < SEQ / KVB) {
            WRITEKV();                           // regs -> LDS
        }
        __syncthreads();                         // tile kt+1 visible
    }

#undef LOADKV
#undef WRITEKV

#pragma unroll
    for (int r = 0; r < 4; ++r) {
        int row = q0 + wave * 16 + quad * 4 + r;
        float rl = 1.0f / __shfl(l_run, quad * 4 + r, 64);
        bf16* op = ao + ((size_t)bb * SEQ + row) * DMODEL + h * 64;
#pragma unroll
        for (int g = 0; g < 4; ++g) op[g * 16 + m] = (bf16)(o_acc[g][r] * rl);
    }
}

// ---------------------------------------------------------------------------
// kernel_launch — fp32 I/O, bf16 internal. ws peak 56 MiB; d_out (32 MB) used
// as scratch (xn/ao in [0,16M), x2n in [16M,32M), final fp32 out last).
// All GEMMs on gemm_bt (128^2) — R5 showed the 4-phase 256^2 was a net loss.
// ---------------------------------------------------------------------------
extern "C" void kernel_launch(void* const* d_in, const int* in_sizes, int n_in,
                              void* d_out, int out_size, void* d_ws, size_t ws_size,
                              hipStream_t stream) {
    const float* x     = (const float*)d_in[0];
    const float* ln1_g = (const float*)d_in[1];
    const float* ln1_b = (const float*)d_in[2];
    const float* w_qkv = (const float*)d_in[3];
    const float* w_out = (const float*)d_in[4];
    const float* b_out = (const float*)d_in[5];
    const float* ln2_g = (const float*)d_in[6];
    const float* ln2_b = (const float*)d_in[7];
    const float* w1    = (const float*)d_in[8];
    const float* b1    = (const float*)d_in[9];
    const float* w2    = (const float*)d_in[10];
    const float* b2    = (const float*)d_in[11];
    float* out = (float*)d_out;
    char* ws = (char*)d_ws;
    char* outc = (char*)d_out;

    bf16* wqkvT = (bf16*)(ws + (0ull << 20));
    bf16* woutT = (bf16*)(ws + (6ull << 20));
    bf16* qkv   = (bf16*)(ws + (8ull << 20));
    bf16* w1T   = (bf16*)(ws + (8ull << 20));    // over dead qkv (after attn)
    bf16* w2T   = (bf16*)(ws + (16ull << 20));   // over dead qkv (after attn)
    float* x2   = (float*)(ws + (24ull << 20));  // over dead qkv (after attn)
    bf16* hbuf  = (bf16*)(ws + (24ull << 20));   // over dead x2 (after ln2)
    bf16* xn    = (bf16*)(outc + 0);             // d_out as scratch
    bf16* ao    = (bf16*)(outc + 0);             // xn dead
    bf16* x2n   = (bf16*)(outc + (16ull << 20)); // upper half of d_out

    dim3 tb(32, 8);
    transpose_f2b<<<dim3(3072 / 32, 1024 / 32), tb, 0, stream>>>(w_qkv, wqkvT, 1024, 3072);
    transpose_f2b<<<dim3(1024 / 32, 1024 / 32), tb, 0, stream>>>(w_out, woutT, 1024, 1024);

    ln_f2b<<<8192, 256, 0, stream>>>(x, ln1_g, ln1_b, xn);
    gemm_bt<<<dim3(3072 / 128, 8192 / 128), 256, 0, stream>>>(xn, wqkvT, nullptr, qkv,
                                                              8192, 3072, 1024, 0);
    attn_mfma<<<dim3(SEQ / 64, 128), 256, 0, stream>>>(qkv, ao);

    transpose_f2b<<<dim3(4096 / 32, 1024 / 32), tb, 0, stream>>>(w1, w1T, 1024, 4096);
    transpose_f2b<<<dim3(1024 / 32, 4096 / 32), tb, 0, stream>>>(w2, w2T, 4096, 1024);

    gemm_bt<<<dim3(1024 / 128, 8192 / 128), 256, 0, stream>>>(ao, woutT, b_out, x2,
                                                              8192, 1024, 1024, 2);
    ln_f2b<<<8192, 256, 0, stream>>>(x2, ln2_g, ln2_b, x2n);

    for (int c = 0; c < 2; ++c) {
        const bf16* a1 = x2n + (size_t)c * 4096 * 1024;
        float* oc = out + (size_t)c * 4096 * 1024;
        gemm_bt<<<dim3(4096 / 128, 4096 / 128), 256, 0, stream>>>(a1, w1T, b1, hbuf,
                                                                  4096, 4096, 1024, 1);
        gemm_bt<<<dim3(1024 / 128, 4096 / 128), 256, 0, stream>>>(hbuf, w2T, b2, oc,
                                                                  4096, 1024, 4096, 2);
    }
}

// Round 18
// 621.744 us; speedup vs baseline: 1.0281x; 1.0281x over previous
//
#include <hip/hip_runtime.h>
#include <hip/hip_bf16.h>
#include <math.h>

typedef __bf16 bf16;
typedef __bf16 bf16x4 __attribute__((ext_vector_type(4)));
typedef __bf16 bf16x8 __attribute__((ext_vector_type(8)));
typedef float f32x4 __attribute__((ext_vector_type(4)));

#define SEQ 1024
#define DMODEL 1024

// async global->LDS DMA, 16B per lane, dest = wave-uniform base + lane*16
__device__ __forceinline__ void gld_lds16(const bf16* g, bf16* l) {
    __builtin_amdgcn_global_load_lds(
        (const __attribute__((address_space(1))) unsigned int*)g,
        (__attribute__((address_space(3))) unsigned int*)l, 16, 0, 0);
}

// ---------------------------------------------------------------------------
// Fused transpose + fp32->bf16 convert: out[n*K + k] = (bf16)in[k*N + n]
// ---------------------------------------------------------------------------
__global__ void transpose_f2b(const float* __restrict__ in, bf16* __restrict__ out,
                              int K, int N) {
    __shared__ float tile[32][33];
    int n0 = blockIdx.x * 32, k0 = blockIdx.y * 32;
    int tx = threadIdx.x, ty = threadIdx.y;
#pragma unroll
    for (int i = 0; i < 4; ++i) {
        int kk = ty + i * 8;
        tile[kk][tx] = in[(size_t)(k0 + kk) * N + n0 + tx];
    }
    __syncthreads();
#pragma unroll
    for (int i = 0; i < 4; ++i) {
        int nn = ty + i * 8;
        out[(size_t)(n0 + nn) * K + k0 + tx] = (bf16)tile[tx][nn];
    }
}

// ---------------------------------------------------------------------------
// LayerNorm: fp32 in -> bf16 out. One row (D=1024) per 256-thread block.
// ---------------------------------------------------------------------------
__global__ void ln_f2b(const float* __restrict__ x, const float* __restrict__ g,
                       const float* __restrict__ bta, bf16* __restrict__ y) {
    int row = blockIdx.x, t = threadIdx.x;
    const float* xr = x + (size_t)row * DMODEL;
    float v[4];
#pragma unroll
    for (int i = 0; i < 4; ++i) v[i] = xr[t * 4 + i];
    float s = v[0] + v[1] + v[2] + v[3];
    float s2 = v[0] * v[0] + v[1] * v[1] + v[2] * v[2] + v[3] * v[3];
#pragma unroll
    for (int off = 32; off > 0; off >>= 1) {
        s += __shfl_down(s, off, 64);
        s2 += __shfl_down(s2, off, 64);
    }
    __shared__ float ws1[4], ws2[4];
    __shared__ float mu_s, rstd_s;
    int lane = t & 63, wv = t >> 6;
    if (lane == 0) { ws1[wv] = s; ws2[wv] = s2; }
    __syncthreads();
    if (t == 0) {
        float S1 = ws1[0] + ws1[1] + ws1[2] + ws1[3];
        float S2 = ws2[0] + ws2[1] + ws2[2] + ws2[3];
        float mu = S1 * (1.0f / DMODEL);
        float var = S2 * (1.0f / DMODEL) - mu * mu;
        mu_s = mu;
        rstd_s = rsqrtf(var + 1e-5f);
    }
    __syncthreads();
    float mu = mu_s, rstd = rstd_s;
    bf16* yr = y + (size_t)row * DMODEL;
#pragma unroll
    for (int i = 0; i < 4; ++i) {
        int d = t * 4 + i;
        float o = (v[i] - mu) * rstd * g[d] + bta[d];
        yr[d] = (bf16)o;
    }
}

// ---------------------------------------------------------------------------
// GEMM (128x128, m97 structure): C[M,N] = A[M,K](bf16) @ Bt[N,K](bf16)^T + bias
// mode: 0 = bf16 out, 1 = bf16 out + exact GELU, 2 = fp32 out
// R14: + T1 XCD-aware chunked block swizzle (m204; verified inside R4's
// gemm256 pass). All grids here have nwg % 8 == 0 -> simple variant exact.
// Consecutive swizzled ids stay on one XCD and walk n0 fastest -> shared
// A-panels (256 KB) become per-XCD L2 hits.
// ---------------------------------------------------------------------------
#define BM 128
#define BN 128
#define BK 32

__global__ __launch_bounds__(256, 2) void gemm_bt(
    const bf16* __restrict__ A, const bf16* __restrict__ Bt,
    const float* __restrict__ bias, void* __restrict__ Cv,
    int M, int N, int K, int mode) {
    __shared__ bf16 sA[BM * BK];   // row-major, 64B rows, chunk-swizzled
    __shared__ bf16 sB[BN * BK];
    int t = threadIdx.x;
    int lane = t & 63, wave = t >> 6;
    int wr = wave >> 1, wc = wave & 1;

    // T1 XCD swizzle (requires nwg % 8 == 0, true for all call sites)
    int nbx = gridDim.x;
    int nwg = nbx * (int)gridDim.y;
    int bid = (int)blockIdx.y * nbx + (int)blockIdx.x;
    int qd = nwg >> 3;
    int wgs = (bid & 7) * qd + (bid >> 3);
    int m0 = (wgs / nbx) * BM, n0 = (wgs % nbx) * BN;

    const bf16* Ap = A + (size_t)m0 * K;
    const bf16* Bp = Bt + (size_t)n0 * K;

    int srow = wave * 16 + (lane >> 2);
    int schunk = lane & 3;
    int gcoff = (schunk ^ (srow & 3)) * 8;
    const bf16* gA0 = Ap + (size_t)srow * K + gcoff;
    const bf16* gA1 = Ap + (size_t)(srow + 64) * K + gcoff;
    const bf16* gB0 = Bp + (size_t)srow * K + gcoff;
    const bf16* gB1 = Bp + (size_t)(srow + 64) * K + gcoff;
    bf16* lA0 = sA + wave * 512;
    bf16* lA1 = sA + 2048 + wave * 512;
    bf16* lB0 = sB + wave * 512;
    bf16* lB1 = sB + 2048 + wave * 512;

    f32x4 acc[4][4];
#pragma unroll
    for (int i = 0; i < 4; ++i)
#pragma unroll
        for (int j = 0; j < 4; ++j) acc[i][j] = (f32x4){0.f, 0.f, 0.f, 0.f};

    int mq = lane & 15, quad = lane >> 4;
    int csw = (quad ^ (mq & 3)) * 8;

    for (int k0 = 0; k0 < K; k0 += BK) {
        __syncthreads();
        gld_lds16(gA0 + k0, lA0);
        gld_lds16(gA1 + k0, lA1);
        gld_lds16(gB0 + k0, lB0);
        gld_lds16(gB1 + k0, lB1);
        __syncthreads();
        bf16x8 af[4], bfr[4];
#pragma unroll
        for (int i = 0; i < 4; ++i)
            af[i] = *(const bf16x8*)&sA[(wr * 64 + i * 16 + mq) * BK + csw];
#pragma unroll
        for (int j = 0; j < 4; ++j)
            bfr[j] = *(const bf16x8*)&sB[(wc * 64 + j * 16 + mq) * BK + csw];
#pragma unroll
        for (int i = 0; i < 4; ++i)
#pragma unroll
            for (int j = 0; j < 4; ++j)
                acc[i][j] = __builtin_amdgcn_mfma_f32_16x16x32_bf16(af[i], bfr[j], acc[i][j], 0, 0, 0);
    }

    int cq = lane & 15, rq = (lane >> 4) * 4;
#pragma unroll
    for (int i = 0; i < 4; ++i) {
        int row = m0 + wr * 64 + i * 16 + rq;
#pragma unroll
        for (int j = 0; j < 4; ++j) {
            int col = n0 + wc * 64 + j * 16 + cq;
            float bv = bias ? bias[col] : 0.0f;
#pragma unroll
            for (int r = 0; r < 4; ++r) {
                float v = acc[i][j][r] + bv;
                if (mode == 1) v = 0.5f * v * (1.0f + erff(v * 0.70710678118654752f));
                size_t idx = (size_t)(row + r) * N + col;
                if (mode == 2) ((float*)Cv)[idx] = v;
                else           ((bf16*)Cv)[idx] = (bf16)v;
            }
        }
    }
}

// ---------------------------------------------------------------------------
// MFMA flash attention — EXACT R9-verified v3 (118.7 us, total 623.6).
// Post-mortems locked in: v4 (P-in-reg mfma16) doubled matrix-pipe time;
// v5 (tr_read) wrong lane layout; v6 (exp2+defer-max) branch broke
// scheduling (+14 us). v3 is the local optimum for this 4-wave structure.
// ---------------------------------------------------------------------------
#define KVB 128
#define LDK2 72     // Klds row pad (d=64 -> 72)
#define LDP 136     // Vt/P row pad (key=128 -> 136)

__global__ __launch_bounds__(256, 2) void attn_mfma(const bf16* __restrict__ qkv,
                                                    bf16* __restrict__ ao) {
    __shared__ bf16 Klds[KVB][LDK2];    // [key][d]   18,432 B
    __shared__ bf16 Vtlds[64][LDP];     // [d][key]   17,408 B
    __shared__ bf16 Plds[4][16][LDP];   // per-wave P [q-row][key] 17,408 B
    int t = threadIdx.x, lane = t & 63, wave = t >> 6;

    // XCD swizzle: 256 consecutive flat ids per XCD -> all 16 q-tiles of a
    // (b,h) share one L2 copy of K/V (R5: FETCH 139->24.7 MB).
    int f = (int)blockIdx.y * (int)gridDim.x + (int)blockIdx.x;  // 0..2047
    int wg = (f & 7) * 256 + (f >> 3);
    int bh = wg >> 4, bb = bh >> 4, h = bh & 15;
    int q0 = (wg & 15) * 64;

    const bf16* base = qkv + (size_t)bb * SEQ * 3072;
    int m = lane & 15, quad = lane >> 4;
    int kq = quad * 8;

    bf16x8 qf[2];
    {
        int qrow = q0 + wave * 16 + m;
        const bf16* p = base + (size_t)qrow * 3072 + h * 64;
#pragma unroll
        for (int c = 0; c < 2; ++c) {
            bf16x8 tmp = *(const bf16x8*)(p + c * 32 + kq);
#pragma unroll
            for (int j = 0; j < 8; ++j) qf[c][j] = (bf16)((float)tmp[j] * 0.125f);
        }
    }

    float m_run = -3e38f, l_run = 0.f;
    f32x4 o_acc[4];
#pragma unroll
    for (int g = 0; g < 4; ++g) o_acc[g] = (f32x4){0.f, 0.f, 0.f, 0.f};

    // staging: thread covers K/V rows skey+{0,32,64,96}, d-slice sd0..sd0+8
    int skey = t >> 3, sd0 = (t & 7) * 8;
    int rot = t & 7;
    const bf16* pk0 = base + (size_t)skey * 3072 + 1024 + h * 64 + sd0;
    const bf16* pv0 = base + (size_t)skey * 3072 + 2048 + h * 64 + sd0;

    bf16x8 kreg[4], vreg[4];

#define LOADKV(kt2) do { \
    const bf16* pk = pk0 + (size_t)(kt2) * KVB * 3072; \
    const bf16* pv = pv0 + (size_t)(kt2) * KVB * 3072; \
    _Pragma("unroll") for (int c = 0; c < 4; ++c) { \
        kreg[c] = *(const bf16x8*)(pk + (size_t)c * 32 * 3072); \
        vreg[c] = *(const bf16x8*)(pv + (size_t)c * 32 * 3072); } \
} while (0)
#define WRITEKV() do { \
    _Pragma("unroll") for (int c = 0; c < 4; ++c) { \
        *(bf16x8*)&Klds[skey + c * 32][sd0] = kreg[c]; \
        _Pragma("unroll") for (int ii = 0; ii < 8; ++ii) { \
            int j = (ii + rot) & 7; \
            Vtlds[sd0 + j][skey + c * 32] = vreg[c][j]; } } \
} while (0)

    // prologue: tile 0 -> LDS
    LOADKV(0);
    WRITEKV();
    __syncthreads();

    for (int kt = 0; kt < SEQ / KVB; ++kt) {   // 8 iterations
        if (kt + 1 < SEQ / KVB) LOADKV(kt + 1);   // T14: issue early

        // swapped QK^T: s[g][r] = P[key=g*16+quad*4+r][q=m]
        f32x4 s[8];
#pragma unroll
        for (int g = 0; g < 8; ++g) {
            bf16x8 b0 = *(const bf16x8*)&Klds[g * 16 + m][kq];
            bf16x8 b1 = *(const bf16x8*)&Klds[g * 16 + m][32 + kq];
            s[g] = (f32x4){0.f, 0.f, 0.f, 0.f};
            s[g] = __builtin_amdgcn_mfma_f32_16x16x32_bf16(b0, qf[0], s[g], 0, 0, 0);
            s[g] = __builtin_amdgcn_mfma_f32_16x16x32_bf16(b1, qf[1], s[g], 0, 0, 0);
        }

        // lane-local online softmax for q-row m
        {
            float mx = s[0][0];
#pragma unroll
            for (int g = 0; g < 8; ++g)
#pragma unroll
                for (int r = 0; r < 4; ++r) mx = fmaxf(mx, s[g][r]);
            mx = fmaxf(mx, __shfl_xor(mx, 16, 64));
            mx = fmaxf(mx, __shfl_xor(mx, 32, 64));
            float m_new = fmaxf(m_run, mx);
            float alpha = __expf(m_run - m_new);
            m_run = m_new;
            float rs = 0.f;
#pragma unroll
            for (int g = 0; g < 8; ++g)
#pragma unroll
                for (int r = 0; r < 4; ++r) {
                    float p = __expf(s[g][r] - m_new);
                    s[g][r] = p;
                    rs += p;
                }
            rs += __shfl_xor(rs, 16, 64);
            rs += __shfl_xor(rs, 32, 64);
            l_run = l_run * alpha + rs;
            // redistribute alpha (row m -> rows quad*4+r held by this lane's acc)
            float av[4];
#pragma unroll
            for (int r = 0; r < 4; ++r) av[r] = __shfl(alpha, quad * 4 + r, 64);
#pragma unroll
            for (int g = 0; g < 4; ++g)
#pragma unroll
                for (int r = 0; r < 4; ++r) o_acc[g][r] *= av[r];
        }

        // P -> LDS: keys g*16+quad*4+{0..3} of row m, one b64 per g
#pragma unroll
        for (int g = 0; g < 8; ++g) {
            bf16x4 pw = {(bf16)s[g][0], (bf16)s[g][1], (bf16)s[g][2], (bf16)s[g][3]};
            *(bf16x4*)&Plds[wave][m][g * 16 + quad * 4] = pw;
        }

        // PV: 4 key-chunks of 32
#pragma unroll
        for (int kc = 0; kc < 4; ++kc) {
            bf16x8 pf = *(const bf16x8*)&Plds[wave][m][kc * 32 + kq];
#pragma unroll
            for (int dg = 0; dg < 4; ++dg) {
                bf16x8 vf = *(const bf16x8*)&Vtlds[dg * 16 + m][kc * 32 + kq];
                o_acc[dg] = __builtin_amdgcn_mfma_f32_16x16x32_bf16(pf, vf, o_acc[dg], 0, 0, 0);
            }
        }

        __syncthreads();                         // all waves done with tile kt
        if (kt + 1 < SEQ / KVB) {
            WRITEKV();                           // regs -> LDS
        }
        __syncthreads();                         // tile kt+1 visible
    }

#undef LOADKV
#undef WRITEKV

#pragma unroll
    for (int r = 0; r < 4; ++r) {
        int row = q0 + wave * 16 + quad * 4 + r;
        float rl = 1.0f / __shfl(l_run, quad * 4 + r, 64);
        bf16* op = ao + ((size_t)bb * SEQ + row) * DMODEL + h * 64;
#pragma unroll
        for (int g = 0; g < 4; ++g) op[g * 16 + m] = (bf16)(o_acc[g][r] * rl);
    }
}

// ---------------------------------------------------------------------------
// kernel_launch — fp32 I/O, bf16 internal. ws peak 56 MiB; d_out (32 MB) used
// as scratch (xn/ao in [0,16M), x2n in [16M,32M), final fp32 out last).
// All GEMMs on gemm_bt (128^2) — R5 showed the 4-phase 256^2 was a net loss.
// ---------------------------------------------------------------------------
extern "C" void kernel_launch(void* const* d_in, const int* in_sizes, int n_in,
                              void* d_out, int out_size, void* d_ws, size_t ws_size,
                              hipStream_t stream) {
    const float* x     = (const float*)d_in[0];
    const float* ln1_g = (const float*)d_in[1];
    const float* ln1_b = (const float*)d_in[2];
    const float* w_qkv = (const float*)d_in[3];
    const float* w_out = (const float*)d_in[4];
    const float* b_out = (const float*)d_in[5];
    const float* ln2_g = (const float*)d_in[6];
    const float* ln2_b = (const float*)d_in[7];
    const float* w1    = (const float*)d_in[8];
    const float* b1    = (const float*)d_in[9];
    const float* w2    = (const float*)d_in[10];
    const float* b2    = (const float*)d_in[11];
    float* out = (float*)d_out;
    char* ws = (char*)d_ws;
    char* outc = (char*)d_out;

    bf16* wqkvT = (bf16*)(ws + (0ull << 20));
    bf16* woutT = (bf16*)(ws + (6ull << 20));
    bf16* qkv   = (bf16*)(ws + (8ull << 20));
    bf16* w1T   = (bf16*)(ws + (8ull << 20));    // over dead qkv (after attn)
    bf16* w2T   = (bf16*)(ws + (16ull << 20));   // over dead qkv (after attn)
    float* x2   = (float*)(ws + (24ull << 20));  // over dead qkv (after attn)
    bf16* hbuf  = (bf16*)(ws + (24ull << 20));   // over dead x2 (after ln2)
    bf16* xn    = (bf16*)(outc + 0);             // d_out as scratch
    bf16* ao    = (bf16*)(outc + 0);             // xn dead
    bf16* x2n   = (bf16*)(outc + (16ull << 20)); // upper half of d_out

    dim3 tb(32, 8);
    transpose_f2b<<<dim3(3072 / 32, 1024 / 32), tb, 0, stream>>>(w_qkv, wqkvT, 1024, 3072);
    transpose_f2b<<<dim3(1024 / 32, 1024 / 32), tb, 0, stream>>>(w_out, woutT, 1024, 1024);

    ln_f2b<<<8192, 256, 0, stream>>>(x, ln1_g, ln1_b, xn);
    gemm_bt<<<dim3(3072 / 128, 8192 / 128), 256, 0, stream>>>(xn, wqkvT, nullptr, qkv,
                                                              8192, 3072, 1024, 0);
    attn_mfma<<<dim3(SEQ / 64, 128), 256, 0, stream>>>(qkv, ao);

    transpose_f2b<<<dim3(4096 / 32, 1024 / 32), tb, 0, stream>>>(w1, w1T, 1024, 4096);
    transpose_f2b<<<dim3(1024 / 32, 4096 / 32), tb, 0, stream>>>(w2, w2T, 4096, 1024);

    gemm_bt<<<dim3(1024 / 128, 8192 / 128), 256, 0, stream>>>(ao, woutT, b_out, x2,
                                                              8192, 1024, 1024, 2);
    ln_f2b<<<8192, 256, 0, stream>>>(x2, ln2_g, ln2_b, x2n);

    for (int c = 0; c < 2; ++c) {
        const bf16* a1 = x2n + (size_t)c * 4096 * 1024;
        float* oc = out + (size_t)c * 4096 * 1024;
        gemm_bt<<<dim3(4096 / 128, 4096 / 128), 256, 0, stream>>>(a1, w1T, b1, hbuf,
                                                                  4096, 4096, 1024, 1);
        gemm_bt<<<dim3(1024 / 128, 4096 / 128), 256, 0, stream>>>(hbuf, w2T, b2, oc,
                                                                  4096, 1024, 4096, 2);
    }
}